// Round 1
// baseline (1039.333 us; speedup 1.0000x reference)
//
#include <hip/hip_runtime.h>
#include <hip/hip_bf16.h>
#include <stdint.h>

#define NTOK 49
#define DIM 128
#define SCALE 0.17677669529663689f  /* 32^-0.5 */

typedef __attribute__((ext_vector_type(4))) float f32x4;
typedef __attribute__((ext_vector_type(2))) unsigned int u32x2;
typedef __attribute__((ext_vector_type(4))) unsigned int u32x4;
typedef __attribute__((ext_vector_type(8))) short bfrag;   // 8 bf16 = 4 VGPRs
typedef __attribute__((ext_vector_type(4))) float facc;    // 4 f32 accum

#define MFMA16(A,B,C) __builtin_amdgcn_mfma_f32_16x16x32_bf16(A,B,C,0,0,0)

__device__ __forceinline__ unsigned pk2bf(float a, float b) {  // RNE pack 2xbf16
    unsigned ua = __builtin_bit_cast(unsigned, a);
    unsigned ub = __builtin_bit_cast(unsigned, b);
    ua = ua + 0x7fffu + ((ua >> 16) & 1u);
    ub = ub + 0x7fffu + ((ub >> 16) & 1u);
    return (ua >> 16) | (ub & 0xffff0000u);
}
__device__ __forceinline__ short f2bf(float a) {
    unsigned ua = __builtin_bit_cast(unsigned, a);
    ua = ua + 0x7fffu + ((ua >> 16) & 1u);
    return (short)(ua >> 16);
}
__device__ __forceinline__ float bf2f(short s) {
    unsigned u = ((unsigned)(unsigned short)s) << 16;
    return __builtin_bit_cast(float, u);
}
// XOR swizzle (T2/G4): spread rows across 16B slots; stride-256B and 128B rows
__device__ __forceinline__ int sw256(int row, int cb) { return row * 256 + (cb ^ ((row & 7) << 4)); }
__device__ __forceinline__ int sw128(int row, int cb) { return row * 128 + (cb ^ ((row & 7) << 4)); }

// ws layout (shorts): Wq 0, Wk 16384, Wv 32768, Wp 49152, RB[4][64][64] 65536
__global__ void prep(const float* __restrict__ Wq, const float* __restrict__ Wk,
                     const float* __restrict__ Wv, const float* __restrict__ Wp,
                     const float* __restrict__ relb, short* __restrict__ ws)
{
    int t = blockIdx.x * 256 + threadIdx.x;
    if (t < 16384) {
        ws[t]         = f2bf(Wq[t]);
        ws[16384 + t] = f2bf(Wk[t]);
        ws[32768 + t] = f2bf(Wv[t]);
        ws[49152 + t] = f2bf(Wp[t]);
        int h = t >> 12, r = (t >> 6) & 63, m = t & 63;
        float v = 0.f;
        if (r < NTOK && m < NTOK) {  // Swin relative-position index, computed inline
            int idx = ((r / 7 - m / 7) + 6) * 13 + ((r % 7) - (m % 7) + 6);
            v = relb[idx * 4 + h];
        }
        ws[65536 + t] = f2bf(v);
    }
}

// One block per window. 4 waves; wave = head for attention phases.
// LDS 64KB: [0,16K) q | [16K,32K) k | (q∪k becomes P[4][64][64]bf16)
//           [32K,48K) vT[128][64]  | [48K,64K) x_bf16 -> mask_f32[64][50] -> att_bf16
__global__ __launch_bounds__(256, 2) void swin_fwd(
    const float* __restrict__ x, const float* __restrict__ mask,
    const float* __restrict__ bq, const float* __restrict__ bk,
    const float* __restrict__ bv, const float* __restrict__ bp,
    const short* __restrict__ wq, const short* __restrict__ wk,
    const short* __restrict__ wv, const short* __restrict__ wp,
    const short* __restrict__ rb, float* __restrict__ out)
{
    extern __shared__ char smem[];
    char* qbuf  = smem;
    char* kbuf  = smem + 16384;
    char* vtbuf = smem + 32768;
    char* r4    = smem + 49152;

    const int win = blockIdx.x;
    const int tid = threadIdx.x;
    const int wid = tid >> 6;
    const int lane = tid & 63;
    const int l16 = lane & 15;
    const int lg = lane >> 4;

    // ---- phase 1: stage x -> r4 bf16 [64][128] swizzled; zero pad rows 49..63
    {
        const float* xw = x + (size_t)win * (NTOK * DIM);
        #pragma unroll
        for (int i = 0; i < 7; ++i) {
            int i4 = i * 256 + tid;
            if (i4 < 1568) {                      // 6272 floats = 1568 float4
                f32x4 f = *(const f32x4*)(xw + i4 * 4);
                int e0 = i4 * 4;
                int tok = e0 >> 7, col = e0 & 127;
                u32x2 w; w.x = pk2bf(f.x, f.y); w.y = pk2bf(f.z, f.w);
                *(u32x2*)(r4 + sw256(tok, col * 2)) = w;
            }
        }
        if (tid < 240) {                          // rows 49..63 = 3840B
            u32x4 z = {0, 0, 0, 0};
            *(u32x4*)(r4 + 49 * 256 + tid * 16) = z;
        }
    }
    __syncthreads();

    // ---- phase 2: QKV. qT/kT GEMM D[o][tok] (natural store -> row-major q,k);
    //               v standard GEMM D[tok][o] (natural store -> vT).
    {
        bfrag aq[2][4], ak[2][4];
        float bqv[2][4], bkv[2][4];
        #pragma unroll
        for (int mt = 0; mt < 2; ++mt) {
            #pragma unroll
            for (int ks = 0; ks < 4; ++ks) {
                int o = wid * 32 + mt * 16 + l16;
                int c = ks * 32 + lg * 8;
                aq[mt][ks] = *(const bfrag*)(wq + o * 128 + c);
                ak[mt][ks] = *(const bfrag*)(wk + o * 128 + c);
            }
            #pragma unroll
            for (int j = 0; j < 4; ++j) {
                int o = wid * 32 + mt * 16 + lg * 4 + j;
                bqv[mt][j] = bq[o];
                bkv[mt][j] = bk[o];
            }
        }
        #pragma unroll
        for (int nt = 0; nt < 4; ++nt) {
            bfrag bx[4];
            #pragma unroll
            for (int ks = 0; ks < 4; ++ks)
                bx[ks] = *(const bfrag*)(r4 + sw256(nt * 16 + l16, (ks * 32 + lg * 8) * 2));
            facc accq[2] = {{0,0,0,0},{0,0,0,0}};
            facc acck[2] = {{0,0,0,0},{0,0,0,0}};
            #pragma unroll
            for (int ks = 0; ks < 4; ++ks)
                #pragma unroll
                for (int mt = 0; mt < 2; ++mt) {
                    accq[mt] = MFMA16(aq[mt][ks], bx[ks], accq[mt]);
                    acck[mt] = MFMA16(ak[mt][ks], bx[ks], acck[mt]);
                }
            int tok = nt * 16 + l16;
            #pragma unroll
            for (int mt = 0; mt < 2; ++mt) {
                int o0 = wid * 32 + mt * 16 + lg * 4;
                u32x2 wq2, wk2;
                wq2.x = pk2bf((accq[mt][0] + bqv[mt][0]) * SCALE, (accq[mt][1] + bqv[mt][1]) * SCALE);
                wq2.y = pk2bf((accq[mt][2] + bqv[mt][2]) * SCALE, (accq[mt][3] + bqv[mt][3]) * SCALE);
                wk2.x = pk2bf(acck[mt][0] + bkv[mt][0], acck[mt][1] + bkv[mt][1]);
                wk2.y = pk2bf(acck[mt][2] + bkv[mt][2], acck[mt][3] + bkv[mt][3]);
                *(u32x2*)(qbuf + sw256(tok, o0 * 2)) = wq2;
                *(u32x2*)(kbuf + sw256(tok, o0 * 2)) = wk2;
            }
        }
        // v: wave strip tok in [wid*16, wid*16+16)
        facc accv[8];
        #pragma unroll
        for (int nt = 0; nt < 8; ++nt) accv[nt] = (facc){0, 0, 0, 0};
        #pragma unroll
        for (int ks = 0; ks < 4; ++ks) {
            bfrag ax = *(const bfrag*)(r4 + sw256(wid * 16 + l16, (ks * 32 + lg * 8) * 2));
            #pragma unroll
            for (int nt = 0; nt < 8; ++nt) {
                bfrag bw = *(const bfrag*)(wv + (nt * 16 + l16) * 128 + ks * 32 + lg * 8);
                accv[nt] = MFMA16(ax, bw, accv[nt]);
            }
        }
        #pragma unroll
        for (int nt = 0; nt < 8; ++nt) {
            int o = nt * 16 + l16;
            float bvo = bv[o];
            int tok0 = wid * 16 + lg * 4;
            u32x2 w;
            w.x = pk2bf(accv[nt][0] + bvo, accv[nt][1] + bvo);
            w.y = pk2bf(accv[nt][2] + bvo, accv[nt][3] + bvo);
            *(u32x2*)(vtbuf + sw128(o, tok0 * 2)) = w;
        }
    }
    __syncthreads();

    // ---- phase 3: stage mask fp32 [64][50] into r4 (x dead) + QK^T (S^T = k·qT)
    float* mlds = (float*)r4;
    {
        const float* mw = mask + (size_t)(win & 1023) * (NTOK * NTOK);
        #pragma unroll
        for (int i = 0; i < 13; ++i) {
            int e = i * 256 + tid;
            if (e < 3200) {
                int r = e / 50, m = e - r * 50;
                mlds[e] = (r < NTOK && m < NTOK) ? mw[r * 49 + m] : 0.f;
            }
        }
    }
    facc s[4][4];   // s[mt][rt]: D[m][r], m=key, r=query; head = wid
    {
        const int h = wid;
        bfrag ka[4], qb[4];
        int cb = (h * 32 + lg * 8) * 2;
        #pragma unroll
        for (int t = 0; t < 4; ++t) {
            ka[t] = *(const bfrag*)(kbuf + sw256(t * 16 + l16, cb));
            qb[t] = *(const bfrag*)(qbuf + sw256(t * 16 + l16, cb));
        }
        #pragma unroll
        for (int mt = 0; mt < 4; ++mt)
            #pragma unroll
            for (int rt = 0; rt < 4; ++rt) {
                facc z = {0, 0, 0, 0};
                s[mt][rt] = MFMA16(ka[mt], qb[rt], z);
            }
    }
    __syncthreads();   // q/k reads + mask writes complete -> P may overwrite q∪k

    // ---- phase 4: softmax over key index m (rows of S^T); write P bf16 [64][64]
    float rs[4];
    {
        const int h = wid;
        const short* rbh = rb + h * 4096;
        char* pbuf = qbuf + h * 8192;   // wave h's P slice inside q∪k (32KB)
        #pragma unroll
        for (int rt = 0; rt < 4; ++rt) {
            int r = rt * 16 + l16;
            float lgt[4][4];
            float mx = -3e38f;
            #pragma unroll
            for (int mt = 0; mt < 4; ++mt)
                #pragma unroll
                for (int j = 0; j < 4; ++j) {
                    int m = mt * 16 + lg * 4 + j;
                    float v = s[mt][rt][j] + bf2f(rbh[r * 64 + m]) + mlds[r * 50 + m];
                    v = (m < NTOK) ? v : -1e30f;   // mask AFTER load (kills any junk)
                    lgt[mt][j] = v;
                    mx = fmaxf(mx, v);
                }
            mx = fmaxf(mx, __shfl_xor(mx, 16));
            mx = fmaxf(mx, __shfl_xor(mx, 32));
            float sum = 0.f;
            u32x2 pw[4];
            #pragma unroll
            for (int mt = 0; mt < 4; ++mt) {
                float p0 = __expf(lgt[mt][0] - mx);
                float p1 = __expf(lgt[mt][1] - mx);
                float p2 = __expf(lgt[mt][2] - mx);
                float p3 = __expf(lgt[mt][3] - mx);
                sum += (p0 + p1) + (p2 + p3);
                pw[mt].x = pk2bf(p0, p1);
                pw[mt].y = pk2bf(p2, p3);
            }
            sum += __shfl_xor(sum, 16);
            sum += __shfl_xor(sum, 32);
            rs[rt] = 1.f / sum;                 // normalization deferred to PV epilogue
            #pragma unroll
            for (int mt = 0; mt < 4; ++mt)
                *(u32x2*)(pbuf + sw128(r, (mt * 16 + lg * 4) * 2)) = pw[mt];
        }
    }
    __syncthreads();

    // ---- phase 5: PV swapped: outT[c][r] = vT · P  -> natural store att[r][c]
    {
        const int h = wid;
        const char* pbuf = qbuf + h * 8192;
        facc o2[2][4];
        #pragma unroll
        for (int ct = 0; ct < 2; ++ct)
            #pragma unroll
            for (int rt = 0; rt < 4; ++rt) o2[ct][rt] = (facc){0, 0, 0, 0};
        #pragma unroll
        for (int ks = 0; ks < 2; ++ks) {
            bfrag av[2], pb[4];
            #pragma unroll
            for (int ct = 0; ct < 2; ++ct)
                av[ct] = *(const bfrag*)(vtbuf + sw128(h * 32 + ct * 16 + l16, (ks * 32 + lg * 8) * 2));
            #pragma unroll
            for (int rt = 0; rt < 4; ++rt)
                pb[rt] = *(const bfrag*)(pbuf + sw128(rt * 16 + l16, (ks * 32 + lg * 8) * 2));
            #pragma unroll
            for (int ct = 0; ct < 2; ++ct)
                #pragma unroll
                for (int rt = 0; rt < 4; ++rt)
                    o2[ct][rt] = MFMA16(av[ct], pb[rt], o2[ct][rt]);
        }
        // att[r][c] bf16 into r4 (mask dead after the phase-4 barrier)
        #pragma unroll
        for (int ct = 0; ct < 2; ++ct) {
            int c0 = h * 32 + ct * 16 + lg * 4;
            #pragma unroll
            for (int rt = 0; rt < 4; ++rt) {
                int r = rt * 16 + l16;
                float sc = rs[rt];
                u32x2 w;
                w.x = pk2bf(o2[ct][rt][0] * sc, o2[ct][rt][1] * sc);
                w.y = pk2bf(o2[ct][rt][2] * sc, o2[ct][rt][3] * sc);
                *(u32x2*)(r4 + sw256(r, c0 * 2)) = w;
            }
        }
    }
    __syncthreads();

    // ---- phase 6: out proj, D[tok][o] = att · WpT, write fp32
    {
        facc acco[8];
        #pragma unroll
        for (int nt = 0; nt < 8; ++nt) acco[nt] = (facc){0, 0, 0, 0};
        #pragma unroll
        for (int ks = 0; ks < 4; ++ks) {
            bfrag aa = *(const bfrag*)(r4 + sw256(wid * 16 + l16, (ks * 32 + lg * 8) * 2));
            #pragma unroll
            for (int nt = 0; nt < 8; ++nt) {
                bfrag bw = *(const bfrag*)(wp + (nt * 16 + l16) * 128 + ks * 32 + lg * 8);
                acco[nt] = MFMA16(aa, bw, acco[nt]);
            }
        }
        float* ow = out + (size_t)win * (NTOK * DIM);
        #pragma unroll
        for (int nt = 0; nt < 8; ++nt) {
            int o = nt * 16 + l16;
            float b = bp[o];
            #pragma unroll
            for (int j = 0; j < 4; ++j) {
                int tok = wid * 16 + lg * 4 + j;
                if (tok < NTOK) ow[tok * 128 + o] = acco[nt][j] + b;
            }
        }
    }
}

extern "C" void kernel_launch(void* const* d_in, const int* in_sizes, int n_in,
                              void* d_out, int out_size, void* d_ws, size_t ws_size,
                              hipStream_t stream)
{
    const float* x    = (const float*)d_in[0];
    const float* mask = (const float*)d_in[1];
    const float* Wq   = (const float*)d_in[2];
    const float* bq   = (const float*)d_in[3];
    const float* Wk   = (const float*)d_in[4];
    const float* bk   = (const float*)d_in[5];
    const float* Wv   = (const float*)d_in[6];
    const float* bv   = (const float*)d_in[7];
    const float* Wp   = (const float*)d_in[8];
    const float* bp   = (const float*)d_in[9];
    const float* rlb  = (const float*)d_in[10];
    short* ws = (short*)d_ws;
    prep<<<64, 256, 0, stream>>>(Wq, Wk, Wv, Wp, rlb, ws);
    swin_fwd<<<16384, 256, 65536, stream>>>(x, mask, bq, bk, bv, bp,
        ws, ws + 16384, ws + 32768, ws + 49152, ws + 65536, (float*)d_out);
}